// Round 4
// baseline (161.273 us; speedup 1.0000x reference)
//
#include <hip/hip_runtime.h>

// Problem: output = embeddings[unseen_index] (200 floats). Only edges with
// edge_dst == unseen_index contribute (~8 of 400000).
//
// Round 6: SINGLE dispatch. Round-3's two-kernel split existed only to
// broadcast the global match list via ws. With the algebraic restructure
//   out[o] = (1/cnt) * sum_r y[r] * basis[r, o],  r = b*IN_DIM+i in [0,1600)
//   y[b*IN_DIM+i] = sum_e att[edge_type_e, b] * xj_e[i]
// blocks own disjoint output columns, so each block can FILTER PRIVATELY:
// 25 blocks x 1024 threads (16 waves/CU = 4/SIMD -> scan latency hidden,
// unlike a 4-wave block). Each block:
//   1. prefetch its 8-col basis slice into regs (13 loads/thread, 51 KB)
//   2. scan all of edge_dst (1.6 MB; L2/L3-resident after first touch,
//      25x40MB L2 traffic ~1.2 us) into a private LDS match list
//   3. per-edge metadata + y[1600] in LDS
//   4. dot with prefetched basis, wave shuffle-reduce, write 8 outputs
// No ws usage at all, no atomics to global, no fences, no memset.

#define DE 200
#define IN_DIM 400
#define NB 4
#define ROWS (NB * IN_DIM)         // 1600
#define CBLOCKS 25
#define CPB 8                      // output cols per block
#define NTHR 1024
#define RG (NTHR / CPB)            // 128 row groups
#define KITER ((ROWS + RG - 1) / RG)   // 13 (last iter partial)
#define NWAVES (NTHR / 64)         // 16
#define PBCAP 64                   // match cap (expected ~8)

__global__ __launch_bounds__(NTHR, 4)
void fused_k(const float* __restrict__ Eemb,
             const float* __restrict__ Remb,
             const float* __restrict__ basis,
             const float* __restrict__ att,
             const int* __restrict__ node_id,
             const int* __restrict__ edge_src,
             const int* __restrict__ edge_dst,
             const int* __restrict__ edge_type,
             const int* __restrict__ rel_index,
             const int* __restrict__ unseen,
             int n_edges,
             float* __restrict__ out)
{
    const int t  = threadIdx.x;
    const int c  = t & (CPB - 1);          // col within block (low bits)
    const int rg = t >> 3;                 // row group 0..127
    const int o  = blockIdx.x * CPB + c;   // output column

    // ---- 1. prefetch basis column slice (latency hides under the scan)
    float rv[KITER];
    #pragma unroll
    for (int k = 0; k < KITER; ++k) {
        const int row = rg + RG * k;
        rv[k] = (row < ROWS) ? basis[(size_t)row * DE + o] : 0.f;
    }

    __shared__ int   s_cnt;
    __shared__ int   s_list[PBCAP];
    __shared__ int   s_srcrow[PBCAP];
    __shared__ int   s_ri[PBCAP];
    __shared__ float s_att[PBCAP][NB];
    __shared__ float s_y[ROWS];
    __shared__ float s_wp[NWAVES * CPB];

    // ---- 2. block-private filter of the full edge list
    if (t == 0) s_cnt = 0;
    __syncthreads();

    const int u  = unseen[0];
    const int n4 = n_edges >> 2;
    const int4* ed4 = (const int4*)edge_dst;
    for (int idx = t; idx < n4; idx += NTHR) {
        const int4 v = ed4[idx];
        const int  e = idx * 4;
        if (v.x == u) { int p = atomicAdd(&s_cnt, 1); if (p < PBCAP) s_list[p] = e;     }
        if (v.y == u) { int p = atomicAdd(&s_cnt, 1); if (p < PBCAP) s_list[p] = e + 1; }
        if (v.z == u) { int p = atomicAdd(&s_cnt, 1); if (p < PBCAP) s_list[p] = e + 2; }
        if (v.w == u) { int p = atomicAdd(&s_cnt, 1); if (p < PBCAP) s_list[p] = e + 3; }
    }
    if (t < (n_edges & 3)) {
        const int e = n4 * 4 + t;
        if (edge_dst[e] == u) { int p = atomicAdd(&s_cnt, 1); if (p < PBCAP) s_list[p] = e; }
    }
    __syncthreads();
    const int cnt_true = s_cnt;
    const int cnt = cnt_true < PBCAP ? cnt_true : PBCAP;

    // ---- 3a. per-edge metadata (parallel over ~8 edges)
    if (t < cnt) {
        const int e = s_list[t];
        s_srcrow[t] = node_id[edge_src[e]];
        s_ri[t]     = rel_index[e];
        const int typ = edge_type[e];
        #pragma unroll
        for (int b = 0; b < NB; ++b) s_att[t][b] = att[typ * NB + b];
    }
    __syncthreads();

    // ---- 3b. y[b*IN_DIM + i] = sum_e att[e,b] * xj_e[i]
    if (t < IN_DIM) {
        float y0 = 0.f, y1 = 0.f, y2 = 0.f, y3 = 0.f;
        for (int j = 0; j < cnt; ++j) {
            const float xv = (t < DE)
                ? Eemb[(size_t)s_srcrow[j] * DE + t]
                : Remb[(size_t)s_ri[j] * DE + (t - DE)];
            y0 += s_att[j][0] * xv;
            y1 += s_att[j][1] * xv;
            y2 += s_att[j][2] * xv;
            y3 += s_att[j][3] * xv;
        }
        s_y[0 * IN_DIM + t] = y0;
        s_y[1 * IN_DIM + t] = y1;
        s_y[2 * IN_DIM + t] = y2;
        s_y[3 * IN_DIM + t] = y3;
    }
    __syncthreads();

    // ---- 4. column dot (8 lanes share each s_y word -> LDS broadcast)
    float acc = 0.f;
    #pragma unroll
    for (int k = 0; k < KITER; ++k) {
        const int row = rg + RG * k;
        if (row < ROWS) acc += rv[k] * s_y[row];
    }

    // intra-wave reduce over the 8 row-groups in each wave (lane&7 == c)
    acc += __shfl_xor(acc, 32);
    acc += __shfl_xor(acc, 16);
    acc += __shfl_xor(acc, 8);
    const int wave = t >> 6;
    if ((t & 63) < CPB) s_wp[wave * CPB + (t & 63)] = acc;
    __syncthreads();

    if (t < CPB) {
        float s = 0.f;
        #pragma unroll
        for (int w = 0; w < NWAVES; ++w) s += s_wp[w * CPB + t];
        int cd = cnt_true < 1 ? 1 : cnt_true;
        out[blockIdx.x * CPB + t] = s / (float)cd;
    }
}

extern "C" void kernel_launch(void* const* d_in, const int* in_sizes, int n_in,
                              void* d_out, int out_size, void* d_ws, size_t ws_size,
                              hipStream_t stream) {
    const float* Eemb  = (const float*)d_in[0];
    const float* Remb  = (const float*)d_in[1];
    const float* basis = (const float*)d_in[2];
    const float* att   = (const float*)d_in[3];
    const int* node_id  = (const int*)d_in[4];
    const int* edge_src = (const int*)d_in[5];
    const int* edge_dst = (const int*)d_in[6];
    const int* edge_typ = (const int*)d_in[7];
    const int* rel_idx  = (const int*)d_in[8];
    const int* unseen   = (const int*)d_in[9];
    float* out = (float*)d_out;

    const int n_edges = in_sizes[6];

    fused_k<<<CBLOCKS, NTHR, 0, stream>>>(Eemb, Remb, basis, att, node_id,
                                          edge_src, edge_dst, edge_typ,
                                          rel_idx, unseen, n_edges, out);
}

// Round 5
// 131.724 us; speedup vs baseline: 1.2243x; 1.2243x over previous
//
#include <hip/hip_runtime.h>

// Problem: output = embeddings[unseen_index] (200 floats). Only edges with
// edge_dst == unseen_index contribute (~8 of 400000 expected).
//
// Round 7: REVERT to the round-3 (132.1 us) two-dispatch structure.
// Established by experiment:
//   - grid.sync ~35 us/sync (r1), __threadfence finalize storm +13 us (r2),
//     narrow-grid redundant edge scan +50 us (r4: 25 CUs x 12.6 B/cy L2
//     drain limit) -- every alternative to the kernel-boundary barrier lost.
//   - r0 (4 nodes) == r3 (2 nodes) within noise: graph-captured node gaps
//     are ~0; controllable kernel time is ~4-6 us of the 132 us total, the
//     rest is harness ws-poison fill (48 us @ 83% HBM peak) + restores.
// Structure:
//   filter_k : 256 blocks scan edge_dst once (int4), write per-block count
//              slots UNCONDITIONALLY (no pre-zeroed counter -> no memset).
//   compute_k: out[o] = (1/cnt) * sum_r y[r] * basis[r,o] with
//              y[b*400+i] = sum_e att[type_e,b] * xj_e[i];
//              50 blocks x 4 cols, basis read exactly once (1.28 MB),
//              basis prefetched to regs before the flatten so HBM latency
//              hides under it. No atomics, no fences, no finalize node.

#define DE 200
#define IN_DIM 400
#define NB 4
#define ROWS (NB * IN_DIM)     // 1600
#define FBLOCKS 256
#define PBCAP 64               // per-filter-block match cap
#define MAXE 128               // flattened match cap (expected ~8)
#define CBLOCKS 50             // compute blocks, 4 output cols each
#define CPB 4                  // cols per block
#define KITER (ROWS / 64)      // 25 rows per thread-rowgroup

// ws layout (32-bit words):
// [0 .. 256)    per-filter-block true counts (always written, no memset)
// [1024 .. )    per-block match lists, PBCAP each
#define WS_CNT_OFF  0
#define WS_LIST_OFF 1024

__global__ __launch_bounds__(256)
void filter_k(const int4* __restrict__ edge_dst4,
              const int* __restrict__ edge_dst,
              const int* __restrict__ unseen,
              int n4, int n_edges,
              int* __restrict__ ws) {
    const int b = blockIdx.x;
    const int t = threadIdx.x;
    __shared__ int s_cnt;
    __shared__ int s_list[PBCAP];
    if (t == 0) s_cnt = 0;
    __syncthreads();

    const int u = unseen[0];
    for (int idx = b * blockDim.x + t; idx < n4; idx += FBLOCKS * blockDim.x) {
        const int4 v = edge_dst4[idx];
        const int  e = idx * 4;
        if (v.x == u) { int p = atomicAdd(&s_cnt, 1); if (p < PBCAP) s_list[p] = e;     }
        if (v.y == u) { int p = atomicAdd(&s_cnt, 1); if (p < PBCAP) s_list[p] = e + 1; }
        if (v.z == u) { int p = atomicAdd(&s_cnt, 1); if (p < PBCAP) s_list[p] = e + 2; }
        if (v.w == u) { int p = atomicAdd(&s_cnt, 1); if (p < PBCAP) s_list[p] = e + 3; }
    }
    if (b == 0 && t < (n_edges & 3)) {
        const int e = n4 * 4 + t;
        if (edge_dst[e] == u) { int p = atomicAdd(&s_cnt, 1); if (p < PBCAP) s_list[p] = e; }
    }
    __syncthreads();
    if (t == 0) ws[WS_CNT_OFF + b] = s_cnt;            // unconditional write
    const int cl = s_cnt < PBCAP ? s_cnt : PBCAP;
    if (t < cl) ws[WS_LIST_OFF + b * PBCAP + t] = s_list[t];
}

__global__ __launch_bounds__(256)
void compute_k(const float* __restrict__ Eemb,
               const float* __restrict__ Remb,
               const float* __restrict__ basis,
               const float* __restrict__ att,
               const int* __restrict__ node_id,
               const int* __restrict__ edge_src,
               const int* __restrict__ edge_type,
               const int* __restrict__ rel_index,
               const int* __restrict__ ws,
               float* __restrict__ out) {
    const int t  = threadIdx.x;
    const int c  = t & 3;                  // col within block
    const int rg = t >> 2;                 // row group 0..63
    const int o  = blockIdx.x * CPB + c;   // output column

    // Issue this thread's 25 basis loads NOW; latency hides under
    // the flatten + y phases below (first use is after the LDS phases).
    float rv[KITER];
    #pragma unroll
    for (int k = 0; k < KITER; ++k)
        rv[k] = basis[(size_t)(rg + 64 * k) * DE + o];

    __shared__ int   s_counts[FBLOCKS];
    __shared__ unsigned long long s_mask[FBLOCKS / 64];
    __shared__ int   s_edges[MAXE];
    __shared__ int   s_srcrow[MAXE];
    __shared__ int   s_ri[MAXE];
    __shared__ float s_att[MAXE][NB];
    __shared__ int   s_total, s_listed;
    __shared__ float s_y[ROWS];            // y[b*400 + i]
    __shared__ float s_part[256];

    // ---- flatten: parallel count load, ballot non-zero, t0 walks set bits
    const int cv = ws[WS_CNT_OFF + t];     // blockDim == FBLOCKS == 256
    s_counts[t] = cv;
    const unsigned long long bal = __ballot(cv > 0);
    if ((t & 63) == 0) s_mask[t >> 6] = bal;
    __syncthreads();
    if (t == 0) {
        int tot = 0, listed = 0;
        for (int w = 0; w < FBLOCKS / 64; ++w) {
            unsigned long long m = s_mask[w];
            while (m) {
                const int bb = w * 64 + __builtin_ctzll(m);
                m &= m - 1;
                const int cb = s_counts[bb];
                tot += cb;
                const int cl = cb < PBCAP ? cb : PBCAP;
                for (int k = 0; k < cl && listed < MAXE; ++k)
                    s_edges[listed++] = ws[WS_LIST_OFF + bb * PBCAP + k];
            }
        }
        s_total  = tot;
        s_listed = listed;
    }
    __syncthreads();
    const int cnt = s_listed;

    // ---- per-edge metadata (parallel over the ~8 edges)
    if (t < cnt) {
        const int e = s_edges[t];
        s_srcrow[t] = node_id[edge_src[e]];
        s_ri[t]     = rel_index[e];
        const int typ = edge_type[e];
        #pragma unroll
        for (int b = 0; b < NB; ++b) s_att[t][b] = att[typ * NB + b];
    }
    __syncthreads();

    // ---- y[b,i] = sum_e att[e,b] * xj_e[i]
    for (int i = t; i < IN_DIM; i += 256) {
        float y0 = 0.f, y1 = 0.f, y2 = 0.f, y3 = 0.f;
        for (int j = 0; j < cnt; ++j) {
            const float xv = (i < DE)
                ? Eemb[(size_t)s_srcrow[j] * DE + i]
                : Remb[(size_t)s_ri[j] * DE + (i - DE)];
            y0 += s_att[j][0] * xv;
            y1 += s_att[j][1] * xv;
            y2 += s_att[j][2] * xv;
            y3 += s_att[j][3] * xv;
        }
        s_y[0 * IN_DIM + i] = y0;
        s_y[1 * IN_DIM + i] = y1;
        s_y[2 * IN_DIM + i] = y2;
        s_y[3 * IN_DIM + i] = y3;
    }
    __syncthreads();

    // ---- column dot: acc = sum_k rv[k] * y[rg + 64k]
    float acc = 0.f;
    #pragma unroll
    for (int k = 0; k < KITER; ++k)
        acc += rv[k] * s_y[rg + 64 * k];   // group-of-4 same addr -> broadcast

    // ---- reduce 64 row-groups per column (offsets multiple of 4 keep c)
    s_part[t] = acc;
    __syncthreads();
    #pragma unroll
    for (int off = 128; off >= 4; off >>= 1) {
        if (t < off) s_part[t] += s_part[t + off];
        __syncthreads();
    }
    if (t < CPB) {
        int cd = s_total;
        if (cd < 1) cd = 1;
        out[blockIdx.x * CPB + t] = s_part[t] / (float)cd;
    }
}

extern "C" void kernel_launch(void* const* d_in, const int* in_sizes, int n_in,
                              void* d_out, int out_size, void* d_ws, size_t ws_size,
                              hipStream_t stream) {
    const float* Eemb  = (const float*)d_in[0];
    const float* Remb  = (const float*)d_in[1];
    const float* basis = (const float*)d_in[2];
    const float* att   = (const float*)d_in[3];
    const int* node_id  = (const int*)d_in[4];
    const int* edge_src = (const int*)d_in[5];
    const int* edge_dst = (const int*)d_in[6];
    const int* edge_typ = (const int*)d_in[7];
    const int* rel_idx  = (const int*)d_in[8];
    const int* unseen   = (const int*)d_in[9];
    float* out = (float*)d_out;
    int*   ws  = (int*)d_ws;

    const int n_edges = in_sizes[6];
    const int n4 = n_edges / 4;

    filter_k<<<FBLOCKS, 256, 0, stream>>>((const int4*)edge_dst, edge_dst,
                                          unseen, n4, n_edges, ws);

    compute_k<<<CBLOCKS, 256, 0, stream>>>(Eemb, Remb, basis, att, node_id,
                                           edge_src, edge_typ, rel_idx,
                                           ws, out);
}